// Round 9
// baseline (2079.122 us; speedup 1.0000x reference)
//
#include <hip/hip_runtime.h>
#include <hip/hip_bf16.h>
#include <math.h>
#include <stdint.h>

#define HID 512
#define NB  512
#define TT  128
#define HOR 24
#define G4  2048
#define SLOT (512*512)

typedef __attribute__((ext_vector_type(8))) short bf16x8;
typedef __attribute__((ext_vector_type(4))) float f32x4;

// flags padded to one 64B line each
#define FL(a, s, gg) ((a) + (((s) * 8 + (gg)) << 4))

// wait for chunk whose loads are all but the newest 4*k vmem ops, then barrier.
// asm with "memory" clobber = compiler fence (R6 lesson), no lgkm/full drain.
#define WAITB(n) asm volatile("s_waitcnt vmcnt(" #n ")\ns_barrier" ::: "memory")

struct PK {
  const float* x;
  const __hip_bfloat16 *W0r, *W1c, *Wd0c, *Wd1c;
  const float *b0r, *b1r, *bd0s0, *bd0r, *bd1r, *Wx0r;
  const float *fcW, *fcb;
  __hip_bfloat16 *h0buf, *h1buf, *dh1buf, *dh2buf;  // unique buffer per step
  const __hip_bfloat16* zbuf;
  int *f0, *f1, *fd1, *fd2;
  float* out;
};

__device__ __forceinline__ void gl_lds16(void* lds, const void* g) {
  __builtin_amdgcn_global_load_lds((const __attribute__((address_space(1))) void*)g,
                                   (__attribute__((address_space(3))) void*)lds, 16, 0, 0);
}

__device__ __forceinline__ float sigm(float x) { return 1.0f / (1.0f + expf(-x)); }

// ---- fence-free dataflow flags (R4/R5/R8-proven protocol) ----
__device__ __forceinline__ void waitflag_nb(int* f) {
  if (threadIdx.x == 0) {
    while (__hip_atomic_load(f, __ATOMIC_RELAXED, __HIP_MEMORY_SCOPE_AGENT) < 32)
      __builtin_amdgcn_s_sleep(1);
  }
  asm volatile("s_barrier" ::: "memory");
}

__device__ __forceinline__ void arrive(int* f) {
  __syncthreads();   // vmcnt(0) drain: h-stores acked at the coherent point (LLC)
  if (threadIdx.x == 0)
    __hip_atomic_fetch_add(f, 1, __ATOMIC_RELAXED, __HIP_MEMORY_SCOPE_AGENT);
}

// ---- register-resident weight fragments (R5-proven layout) ----
template<int KC>
__device__ __forceinline__ void load_w(bf16x8* Breg, const __hip_bfloat16* W,
                                       int Kt, int nrow, int q) {
  const char* base = (const char*)W + ((size_t)nrow * Kt + q * 8) * 2;
#pragma unroll
  for (int kc = 0; kc < KC; ++kc)
    Breg[kc] = *(const bf16x8*)(base + (size_t)kc * 64);
}

// ---- staging + MFMA primitives (R8-verified addressing) ----
__device__ __forceinline__ void stage_chunk(const __hip_bfloat16* As, int kloc,
                                            char* dst, int m0, int tid) {
#pragma unroll
  for (int i = 0; i < 4; ++i) {
    const int u = (i << 8) + tid;          // 0..1023 ; unit = octet*64 + row
    const int o = u >> 6, r = u & 63;
    gl_lds16(dst + (size_t)u * 16, As + (size_t)(m0 + r) * 512 + kloc + (o << 3));
  }
}

__device__ __forceinline__ void mfma_chunk(const char* sA, const bf16x8* Breg, int bb,
                                           int q, int s, f32x4* acc) {
#pragma unroll
  for (int kl = 0; kl < 4; ++kl) {
#pragma unroll
    for (int mi = 0; mi < 4; ++mi) {
      bf16x8 a = *(const bf16x8*)(sA +
          (size_t)((((kl << 2) + q) << 6) + (mi << 4) + s) * 16);
      acc[mi] = __builtin_amdgcn_mfma_f32_16x16x32_bf16(a, Breg[bb + kl], acc[mi], 0, 0, 0);
    }
  }
}

// ---- K=512 GEMM (role A encoder): 4 chunks through 4 LDS buffers ----
__device__ __forceinline__ void gemm4(const __hip_bfloat16* Af, const bf16x8* Breg,
                                      int m0, char* smem, int lane, f32x4* acc) {
  const int tid = threadIdx.x;
  const int s = lane & 15, q = lane >> 4;
#pragma unroll
  for (int mi = 0; mi < 4; ++mi) acc[mi] = (f32x4){0.f, 0.f, 0.f, 0.f};
  stage_chunk(Af, 0,   smem,         m0, tid);
  stage_chunk(Af, 128, smem + 16384, m0, tid);
  stage_chunk(Af, 256, smem + 32768, m0, tid);
  WAITB(8); stage_chunk(Af, 384, smem + 49152, m0, tid);
            mfma_chunk(smem,         Breg, 0,  q, s, acc);
  WAITB(8); mfma_chunk(smem + 16384, Breg, 4,  q, s, acc);
  WAITB(4); mfma_chunk(smem + 32768, Breg, 8,  q, s, acc);
  WAITB(0); mfma_chunk(smem + 49152, Breg, 12, q, s, acc);
}

// ---- K=1024 GEMM, half-swapped: first half (Af, own-flag — caller already
// waited) streams immediately; cross flag f2 is polled mid-GEMM before the
// second half (As2) is staged, overlapping the cross hand-off with compute.
// bo1/bo2 select the Breg range matching each half's K-columns. ----
__device__ __forceinline__ void gemm8(
    const __hip_bfloat16* Af, int bo1,
    const __hip_bfloat16* As2, int bo2, int* f2,
    const bf16x8* Breg, int m0, char* smem, int lane, f32x4* acc) {
  const int tid = threadIdx.x;
  const int s = lane & 15, q = lane >> 4;
#pragma unroll
  for (int mi = 0; mi < 4; ++mi) acc[mi] = (f32x4){0.f, 0.f, 0.f, 0.f};
  stage_chunk(Af, 0,   smem,         m0, tid);
  stage_chunk(Af, 128, smem + 16384, m0, tid);
  stage_chunk(Af, 256, smem + 32768, m0, tid);
  WAITB(8); stage_chunk(Af, 384, smem + 49152, m0, tid);          // in flight 1,2,3
            mfma_chunk(smem,         Breg, bo1 + 0,  q, s, acc);
  WAITB(8); mfma_chunk(smem + 16384, Breg, bo1 + 4,  q, s, acc);  // in flight 2,3
  WAITB(4);                                                       // in flight 3
  if (f2) waitflag_nb(f2);                 // cross hand-off gate (second half)
  stage_chunk(As2, 0,   smem,         m0, tid);                   // buf0 (read @c0)
  stage_chunk(As2, 128, smem + 16384, m0, tid);                   // buf1 (read @c1)
            mfma_chunk(smem + 32768, Breg, bo1 + 8,  q, s, acc);
  WAITB(8); stage_chunk(As2, 256, smem + 32768, m0, tid);         // in flight 4,5 -> +6
            mfma_chunk(smem + 49152, Breg, bo1 + 12, q, s, acc);
  WAITB(8); stage_chunk(As2, 384, smem + 49152, m0, tid);         // in flight 5,6 -> +7
            mfma_chunk(smem,         Breg, bo2 + 0,  q, s, acc);
  WAITB(8); mfma_chunk(smem + 16384, Breg, bo2 + 4,  q, s, acc);  // in flight 6,7
  WAITB(4); mfma_chunk(smem + 32768, Breg, bo2 + 8,  q, s, acc);  // in flight 7
  WAITB(0); mfma_chunk(smem + 49152, Breg, bo2 + 12, q, s, acc);
}

// ---- fused LSTM epilogue (R8 aliasing-safe regather). Key R9 change: h-stores
// at AGENT scope — device-coherent point is the LLC; consumers LLC-hit instead
// of HBM-miss, and arrive()'s drain waits on LLC acks, not HBM. ----
__device__ __forceinline__ void epilogue(
    const f32x4* __restrict__ acc, float* __restrict__ tbuf, ushort* __restrict__ hsh,
    const f32x4 bz, const f32x4* w01, const f32x4* w23, const float2* xr,
    float* __restrict__ creg, __hip_bfloat16* __restrict__ hout,
    int m0, int colbase, int lane) {
  const int s = lane & 15, q = lane >> 4;
  const int row_e = lane >> 2, jl = lane & 3;
#pragma unroll
  for (int mi = 0; mi < 4; ++mi) {
#pragma unroll
    for (int r = 0; r < 4; ++r)
      tbuf[mi * 320 + (q * 4 + r) * 20 + s] = acc[mi][r];
  }
#pragma unroll
  for (int mi = 0; mi < 4; ++mi) {
    f32x4 gv = *(const f32x4*)&tbuf[mi * 320 + row_e * 20 + jl * 4];
    float gi = gv[0] + bz[0], gf = gv[1] + bz[1];
    float gg = gv[2] + bz[2], go = gv[3] + bz[3];
    if (xr) {
      gi += xr[mi].x * (*w01)[0] + xr[mi].y * (*w01)[1];
      gf += xr[mi].x * (*w01)[2] + xr[mi].y * (*w01)[3];
      gg += xr[mi].x * (*w23)[0] + xr[mi].y * (*w23)[1];
      go += xr[mi].x * (*w23)[2] + xr[mi].y * (*w23)[3];
    }
    float iv = sigm(gi), fv = sigm(gf), gvv = tanhf(gg), ov = sigm(go);
    float cv = fv * creg[mi] + iv * gvv;
    creg[mi] = cv;
    __hip_bfloat16 hv = __float2bfloat16(ov * tanhf(cv));
    hsh[(mi << 6) + lane] = __builtin_bit_cast(unsigned short, hv);
  }
  unsigned long long pk;
  asm volatile("" ::: "memory");
  __builtin_memcpy(&pk, &hsh[lane << 2], 8);        // aliasing-safe packed read
  __hip_atomic_store((unsigned long long*)&hout[(size_t)(m0 + lane) * 512 + colbase],
                     pk, __ATOMIC_RELAXED, __HIP_MEMORY_SCOPE_AGENT);
}

// pred spread over all 32 sibling blocks: 2 batch rows each (no straggler)
__device__ __forceinline__ void pred_job2(const __hip_bfloat16* h2, const float* fcW,
                                          const float* fcb, float* outp,
                                          int d2, int g, int nt) {
  const int wv = threadIdx.x >> 6, lane = threadIdx.x & 63;
  if (wv < 2) {
    int b = g * 64 + nt * 2 + wv;
    float s0 = 0.f, s1 = 0.f;
    for (int k = lane; k < 512; k += 64) {
      float hv = __bfloat162float(h2[(size_t)b * 512 + k]);
      s0 += hv * fcW[k];
      s1 += hv * fcW[512 + k];
    }
    for (int off = 32; off; off >>= 1) {
      s0 += __shfl_down(s0, off);
      s1 += __shfl_down(s1, off);
    }
    if (lane == 0) {
      outp[(size_t)b * (HOR * 2) + d2 * 2]     = s0 + fcb[0];
      outp[(size_t)b * (HOR * 2) + d2 * 2 + 1] = s1 + fcb[1];
    }
  }
}

// Persistent kernel: 512 blocks, 2/CU by construction (LDS 64 KB, VGPR capped).
__global__ __launch_bounds__(256, 2) void seq2seq_persistent(PK p) {
  __shared__ __align__(16) char smem[65536];   // 4x16KB staging; tbuf/hsh alias
  const int blk = blockIdx.x;
  const int g = blk & 7;
  const int role = (blk >> 3) & 1;
  const int nt = blk >> 4;                     // 0..31 gate-col tile
  const int m0 = g * 64;
  const int wv = threadIdx.x >> 6, lane = threadIdx.x & 63;
  const int s16 = lane & 15, q = lane >> 4;
  const int nrow = nt * 64 + wv * 16 + s16;    // B-frag gate-col row
  const int jl = lane & 3;
  const int jg = nt * 16 + wv * 4 + jl;        // h column this lane owns
  const int n4 = jg * 4;
  const int colbase = nt * 16 + wv * 4;
  float* tbuf = (float*)(smem) + wv * 1280;            // per-wave 5 KB
  ushort* hsh = (ushort*)(smem + 20480) + wv * 256;    // per-wave 512 B

  f32x4 acc[4];
  bf16x8 Breg[32];                             // 128 regs of weights
  float creg[4] = {0.f, 0.f, 0.f, 0.f};        // cell state, register-resident

  if (role == 1) {
    // ---- role B: encoder layer1, decoder cell2. Own-flag half (h1/dh2 prev,
    // W cols 512..1023 = Breg[16..31]) first; cross flag polled mid-GEMM. ----
    load_w<32>(Breg, p.W1c, 1024, nrow, q);
    f32x4 bz = *(const f32x4*)&p.b1r[n4];
    for (int u = 0; u < TT; ++u) {
      if (u >= 1) waitflag_nb(FL(p.f1, u - 1, g));   // own sibling barrier
      const __hip_bfloat16* Af = (u == 0) ? p.zbuf : p.h1buf + (size_t)(u - 1) * SLOT;
      gemm8(Af, 16, p.h0buf + (size_t)u * SLOT, 0, FL(p.f0, u, g),
            Breg, m0, smem, lane, acc);
      epilogue(acc, tbuf, hsh, bz, nullptr, nullptr, nullptr, creg,
               p.h1buf + (size_t)u * SLOT, m0, colbase, lane);
      arrive(FL(p.f1, u, g));
    }
    load_w<32>(Breg, p.Wd1c, 1024, nrow, q);
    bz = *(const f32x4*)&p.bd1r[n4];
    for (int d = 0; d < HOR; ++d) {
      if (d == 0) waitflag_nb(FL(p.f1, 127, g));
      else        waitflag_nb(FL(p.fd2, d - 1, g));  // own sibling barrier
      const __hip_bfloat16* Af = (d == 0) ? p.h1buf + (size_t)127 * SLOT
                                          : p.dh2buf + (size_t)(d - 1) * SLOT;
      gemm8(Af, 16, p.dh1buf + (size_t)d * SLOT, 0, FL(p.fd1, d, g),
            Breg, m0, smem, lane, acc);
      epilogue(acc, tbuf, hsh, bz, nullptr, nullptr, nullptr, creg,
               p.dh2buf + (size_t)d * SLOT, m0, colbase, lane);
      arrive(FL(p.fd2, d, g));
    }
  } else {
    // ---- role A: encoder layer0 (K=512), decoder cell1 (pred folded) ----
    load_w<16>(Breg, p.W0r, 512, nrow, q);
    f32x4 bz = *(const f32x4*)&p.b0r[n4];
    f32x4 w01 = *(const f32x4*)&p.Wx0r[n4 * 2];
    f32x4 w23 = *(const f32x4*)&p.Wx0r[n4 * 2 + 4];
    const int row_e = lane >> 2;
    for (int s = 0; s < TT; ++s) {
      if (s >= 1) waitflag_nb(FL(p.f0, s - 1, g));
      gemm4((s == 0) ? p.zbuf : p.h0buf + (size_t)(s - 1) * SLOT,
            Breg, m0, smem, lane, acc);
      float2 xr[4];
#pragma unroll
      for (int mi = 0; mi < 4; ++mi)
        xr[mi] = *(const float2*)&p.x[((size_t)(m0 + mi * 16 + row_e) * TT + s) * 2];
      epilogue(acc, tbuf, hsh, bz, &w01, &w23, xr, creg,
               p.h0buf + (size_t)s * SLOT, m0, colbase, lane);
      arrive(FL(p.f0, s, g));
    }
    load_w<32>(Breg, p.Wd0c, 1024, nrow, q);
    f32x4 bzd0 = *(const f32x4*)&p.bd0s0[n4];
    f32x4 bzd  = *(const f32x4*)&p.bd0r[n4];
    for (int d = 0; d < HOR; ++d) {
      const __hip_bfloat16 *Af, *As2; int* f2; f32x4 bzu;
      if (d == 0) {
        waitflag_nb(FL(p.f0, 127, g));
        Af = p.h0buf + (size_t)127 * SLOT; As2 = p.zbuf; f2 = nullptr; bzu = bzd0;
      } else {
        waitflag_nb(FL(p.fd1, d - 1, g));            // own sibling barrier
        Af  = p.dh1buf + (size_t)(d - 1) * SLOT;     // dh1-prev half first (Breg 0..15)
        As2 = p.dh2buf + (size_t)(d - 1) * SLOT;     // dh2 half gated on cross flag
        f2 = FL(p.fd2, d - 1, g); bzu = bzd;
      }
      gemm8(Af, 0, As2, 16, f2, Breg, m0, smem, lane, acc);
      epilogue(acc, tbuf, hsh, bzu, nullptr, nullptr, nullptr, creg,
               p.dh1buf + (size_t)d * SLOT, m0, colbase, lane);
      arrive(FL(p.fd1, d, g));
      if (d >= 1)
        pred_job2(p.dh2buf + (size_t)(d - 1) * SLOT, p.fcW, p.fcb, p.out, d - 1, g, nt);
    }
    waitflag_nb(FL(p.fd2, 23, g));
    pred_job2(p.dh2buf + (size_t)23 * SLOT, p.fcW, p.fcb, p.out, 23, g, nt);
  }
}

// Build gate-interleaved bf16 weights, combined biases, and the pred-fold:
// Wd0c[:,512:1024] = dWih0 @ fcW  (rank-2 fold of decoder feedback)
__global__ void prep_weights(
    const float* eWih0, const float* eWhh0, const float* ebih0, const float* ebhh0,
    const float* eWih1, const float* eWhh1, const float* ebih1, const float* ebhh1,
    const float* dWih0, const float* dWhh0, const float* dbih0, const float* dbhh0,
    const float* dWih1, const float* dWhh1, const float* dbih1, const float* dbhh1,
    const float* fcW, const float* fcb,
    __hip_bfloat16* W0r, __hip_bfloat16* W1c, __hip_bfloat16* Wd0c, __hip_bfloat16* Wd1c,
    float* b0r, float* b1r, float* bd0s0, float* bd0r, float* bd1r, float* Wx0r) {
  long idx = (long)blockIdx.x * blockDim.x + threadIdx.x;
  if (idx >= (long)G4 * 3584) return;
  int np = (int)(idx / 3584), kk = (int)(idx % 3584);
  int g = np & 3, j = np >> 2;
  int srow = g * HID + j;
  if (kk < 512) {
    W0r[(size_t)np * 512 + kk] = __float2bfloat16(eWhh0[(size_t)srow * 512 + kk]);
  } else if (kk < 1536) {
    int k2 = kk - 512;
    float v = (k2 < 512) ? eWih1[(size_t)srow * 512 + k2] : eWhh1[(size_t)srow * 512 + (k2 - 512)];
    W1c[(size_t)np * 1024 + k2] = __float2bfloat16(v);
  } else if (kk < 2560) {
    int k2 = kk - 1536;
    float v;
    if (k2 < 512) v = dWhh0[(size_t)srow * 512 + k2];
    else {
      int k3 = k2 - 512;
      v = dWih0[srow * 2] * fcW[k3] + dWih0[srow * 2 + 1] * fcW[512 + k3];
    }
    Wd0c[(size_t)np * 1024 + k2] = __float2bfloat16(v);
  } else {
    int k2 = kk - 2560;
    float v = (k2 < 512) ? dWih1[(size_t)srow * 512 + k2] : dWhh1[(size_t)srow * 512 + (k2 - 512)];
    Wd1c[(size_t)np * 1024 + k2] = __float2bfloat16(v);
  }
  if (kk == 0) {
    b0r[np] = ebih0[srow] + ebhh0[srow];
    b1r[np] = ebih1[srow] + ebhh1[srow];
    float bs0 = dbih0[srow] + dbhh0[srow];
    bd0s0[np] = bs0;
    bd0r[np] = bs0 + dWih0[srow * 2] * fcb[0] + dWih0[srow * 2 + 1] * fcb[1];
    bd1r[np] = dbih1[srow] + dbhh1[srow];
    Wx0r[np * 2]     = eWih0[srow * 2];
    Wx0r[np * 2 + 1] = eWih0[srow * 2 + 1];
  }
}

extern "C" void kernel_launch(void* const* d_in, const int* in_sizes, int n_in,
                              void* d_out, int out_size, void* d_ws, size_t ws_size,
                              hipStream_t stream) {
  (void)in_sizes; (void)n_in; (void)out_size; (void)ws_size;
  const float* x     = (const float*)d_in[0];
  const float* eWih0 = (const float*)d_in[1];
  const float* eWhh0 = (const float*)d_in[2];
  const float* ebih0 = (const float*)d_in[3];
  const float* ebhh0 = (const float*)d_in[4];
  const float* eWih1 = (const float*)d_in[5];
  const float* eWhh1 = (const float*)d_in[6];
  const float* ebih1 = (const float*)d_in[7];
  const float* ebhh1 = (const float*)d_in[8];
  const float* dWih0 = (const float*)d_in[9];
  const float* dWhh0 = (const float*)d_in[10];
  const float* dbih0 = (const float*)d_in[11];
  const float* dbhh0 = (const float*)d_in[12];
  const float* dWih1 = (const float*)d_in[13];
  const float* dWhh1 = (const float*)d_in[14];
  const float* dbih1 = (const float*)d_in[15];
  const float* dbhh1 = (const float*)d_in[16];
  const float* fcW   = (const float*)d_in[17];
  const float* fcb   = (const float*)d_in[18];

  char* ws = (char*)d_ws;
  size_t off = 0;
  auto alloc = [&](size_t bytes) -> char* {
    char* pp = ws + off;
    off = (off + bytes + 255) & ~(size_t)255;
    return pp;
  };

  __hip_bfloat16* W0r  = (__hip_bfloat16*)alloc((size_t)G4 * 512 * 2);
  __hip_bfloat16* W1c  = (__hip_bfloat16*)alloc((size_t)G4 * 1024 * 2);
  __hip_bfloat16* Wd0c = (__hip_bfloat16*)alloc((size_t)G4 * 1024 * 2);
  __hip_bfloat16* Wd1c = (__hip_bfloat16*)alloc((size_t)G4 * 1024 * 2);
  float* b0r   = (float*)alloc(G4 * 4);
  float* b1r   = (float*)alloc(G4 * 4);
  float* bd0s0 = (float*)alloc(G4 * 4);
  float* bd0r  = (float*)alloc(G4 * 4);
  float* bd1r  = (float*)alloc(G4 * 4);
  float* Wx0r  = (float*)alloc(G4 * 2 * 4);

  __hip_bfloat16* h0buf  = (__hip_bfloat16*)alloc((size_t)TT * SLOT * 2);
  __hip_bfloat16* h1buf  = (__hip_bfloat16*)alloc((size_t)TT * SLOT * 2);
  __hip_bfloat16* dh1buf = (__hip_bfloat16*)alloc((size_t)HOR * SLOT * 2);
  __hip_bfloat16* dh2buf = (__hip_bfloat16*)alloc((size_t)HOR * SLOT * 2);

  char* zbase = ws + off;
  __hip_bfloat16* zbuf = (__hip_bfloat16*)alloc((size_t)SLOT * 2);
  int* f0  = (int*)alloc(TT * 8 * 16 * 4);
  int* f1  = (int*)alloc(TT * 8 * 16 * 4);
  int* fd1 = (int*)alloc(HOR * 8 * 16 * 4);
  int* fd2 = (int*)alloc(HOR * 8 * 16 * 4);
  size_t zbytes = (size_t)((ws + off) - zbase);

  hipMemsetAsync(zbase, 0, zbytes, stream);
  prep_weights<<<(int)(((long)G4 * 3584 + 255) / 256), 256, 0, stream>>>(
      eWih0, eWhh0, ebih0, ebhh0, eWih1, eWhh1, ebih1, ebhh1,
      dWih0, dWhh0, dbih0, dbhh0, dWih1, dWhh1, dbih1, dbhh1,
      fcW, fcb, W0r, W1c, Wd0c, Wd1c, b0r, b1r, bd0s0, bd0r, bd1r, Wx0r);

  PK p;
  p.x = x;
  p.W0r = W0r; p.W1c = W1c; p.Wd0c = Wd0c; p.Wd1c = Wd1c;
  p.b0r = b0r; p.b1r = b1r; p.bd0s0 = bd0s0; p.bd0r = bd0r; p.bd1r = bd1r; p.Wx0r = Wx0r;
  p.fcW = fcW; p.fcb = fcb;
  p.h0buf = h0buf; p.h1buf = h1buf; p.dh1buf = dh1buf; p.dh2buf = dh2buf;
  p.zbuf = zbuf;
  p.f0 = f0; p.f1 = f1; p.fd1 = fd1; p.fd2 = fd2;
  p.out = (float*)d_out;

  seq2seq_persistent<<<512, 256, 0, stream>>>(p);
}

// Round 10
// 1316.585 us; speedup vs baseline: 1.5792x; 1.5792x over previous
//
#include <hip/hip_runtime.h>
#include <hip/hip_bf16.h>
#include <math.h>
#include <stdint.h>

#define HID 512
#define NB  512
#define TT  128
#define HOR 24
#define G4  2048
#define SLOT (512*512)

typedef __attribute__((ext_vector_type(8))) short bf16x8;
typedef __attribute__((ext_vector_type(4))) float f32x4;

// flags padded to one 64B line each
#define FL(a, s, gg) ((a) + (((s) * 8 + (gg)) << 4))

// wait until at most N vmem ops outstanding, then barrier. asm with "memory"
// clobber = compiler fence (R6 lesson). FIFO vmcnt semantics make stray extra
// vmem ops only cause over-draining (audited R7/R8).
#define WAITB(n) asm volatile("s_waitcnt vmcnt(" #n ")\ns_barrier" ::: "memory")

struct PK {
  const float* x;
  const __hip_bfloat16 *W0r, *W1c, *Wd0c, *Wd1c;
  const float *b0r, *b1r, *bd0s0, *bd0r, *bd1r, *Wx0r;
  const float *fcW, *fcb;
  __hip_bfloat16 *h0buf, *h1buf, *dh1buf, *dh2buf;  // unique buffer per step, OCTET layout
  const __hip_bfloat16* zbuf;
  int *f0, *f1, *fd1, *fd2;
  float* out;
};

__device__ __forceinline__ void gl_lds16(void* lds, const void* g) {
  __builtin_amdgcn_global_load_lds((const __attribute__((address_space(1))) void*)g,
                                   (__attribute__((address_space(3))) void*)lds, 16, 0, 0);
}

__device__ __forceinline__ float sigm(float x) { return 1.0f / (1.0f + expf(-x)); }

// ---- fence-free dataflow flags (R4/R5/R8-proven protocol) ----
__device__ __forceinline__ void waitflag_nb(int* f) {
  if (threadIdx.x == 0) {
    while (__hip_atomic_load(f, __ATOMIC_RELAXED, __HIP_MEMORY_SCOPE_AGENT) < 32)
      __builtin_amdgcn_s_sleep(1);
  }
  asm volatile("s_barrier" ::: "memory");
}

__device__ __forceinline__ void arrive(int* f) {
  __syncthreads();   // vmcnt(0) drain: h-stores acked at coherent point
  if (threadIdx.x == 0)
    __hip_atomic_fetch_add(f, 1, __ATOMIC_RELAXED, __HIP_MEMORY_SCOPE_AGENT);
}

// ---- register-resident weight fragments (R5-proven layout) ----
template<int KC>
__device__ __forceinline__ void load_w(bf16x8* Breg, const __hip_bfloat16* W,
                                       int Kt, int nrow, int q) {
  const char* base = (const char*)W + ((size_t)nrow * Kt + q * 8) * 2;
#pragma unroll
  for (int kc = 0; kc < KC; ++kc)
    Breg[kc] = *(const bf16x8*)(base + (size_t)kc * 64);
}

// ---- OCTET h layout: buffer per (step) = 8 groups x 4 chunks x 16 octets x
// 64 rows x 16B. Consumer staging is fully sequential; producer writes are
// full-line coalesced. goff = g*4. ----
__device__ __forceinline__ void stage_chunk(const __hip_bfloat16* As, int c,
                                            char* dst, int goff, int tid) {
  const __hip_bfloat16* base = As + ((size_t)(goff + c) << 13);
#pragma unroll
  for (int i = 0; i < 4; ++i) {
    const int u = (i << 8) + tid;
    gl_lds16(dst + (size_t)u * 16, base + ((size_t)u << 3));
  }
}

__device__ __forceinline__ void mfma_chunk(const char* sA, const bf16x8* Breg, int bb,
                                           int q, int s, f32x4* acc) {
#pragma unroll
  for (int kl = 0; kl < 4; ++kl) {
#pragma unroll
    for (int mi = 0; mi < 4; ++mi) {
      bf16x8 a = *(const bf16x8*)(sA +
          (size_t)((((kl << 2) + q) << 6) + (mi << 4) + s) * 16);
      acc[mi] = __builtin_amdgcn_mfma_f32_16x16x32_bf16(a, Breg[bb + kl], acc[mi], 0, 0, 0);
    }
  }
}

// ---- K=512 GEMM (role A encoder): 4 chunks through 4 LDS buffers ----
__device__ __forceinline__ void gemm4(const __hip_bfloat16* Af, const bf16x8* Breg,
                                      int goff, char* smem, int lane, f32x4* acc) {
  const int tid = threadIdx.x;
  const int s = lane & 15, q = lane >> 4;
#pragma unroll
  for (int mi = 0; mi < 4; ++mi) acc[mi] = (f32x4){0.f, 0.f, 0.f, 0.f};
  stage_chunk(Af, 0, smem,         goff, tid);
  stage_chunk(Af, 1, smem + 16384, goff, tid);
  stage_chunk(Af, 2, smem + 32768, goff, tid);
  WAITB(8); stage_chunk(Af, 3, smem + 49152, goff, tid);
            mfma_chunk(smem,         Breg, 0,  q, s, acc);
  WAITB(8); mfma_chunk(smem + 16384, Breg, 4,  q, s, acc);
  WAITB(4); mfma_chunk(smem + 32768, Breg, 8,  q, s, acc);
  WAITB(0); mfma_chunk(smem + 49152, Breg, 12, q, s, acc);
}

// ---- K=1024 GEMM, half-swapped: Af (early/available input) streams first;
// f2 (the LATE dependency's flag) is polled mid-GEMM before staging As2 —
// overlapping the critical hand-off with Af compute (R8 lesson). ----
__device__ __forceinline__ void gemm8(
    const __hip_bfloat16* Af, int bo1,
    const __hip_bfloat16* As2, int bo2, int* f2,
    const bf16x8* Breg, int goff, char* smem, int lane, f32x4* acc) {
  const int tid = threadIdx.x;
  const int s = lane & 15, q = lane >> 4;
#pragma unroll
  for (int mi = 0; mi < 4; ++mi) acc[mi] = (f32x4){0.f, 0.f, 0.f, 0.f};
  stage_chunk(Af, 0, smem,         goff, tid);
  stage_chunk(Af, 1, smem + 16384, goff, tid);
  stage_chunk(Af, 2, smem + 32768, goff, tid);
  WAITB(8); stage_chunk(Af, 3, smem + 49152, goff, tid);          // in flight 1,2,3
            mfma_chunk(smem,         Breg, bo1 + 0,  q, s, acc);
  WAITB(8); mfma_chunk(smem + 16384, Breg, bo1 + 4,  q, s, acc);  // in flight 2,3
  WAITB(4);                                                       // in flight 3
  if (f2) waitflag_nb(f2);                 // LATE dependency gate (second half)
  stage_chunk(As2, 0, smem,         goff, tid);                   // buf0 (read @c0)
  stage_chunk(As2, 1, smem + 16384, goff, tid);                   // buf1 (read @c1)
            mfma_chunk(smem + 32768, Breg, bo1 + 8,  q, s, acc);
  WAITB(8); stage_chunk(As2, 2, smem + 32768, goff, tid);
            mfma_chunk(smem + 49152, Breg, bo1 + 12, q, s, acc);
  WAITB(8); stage_chunk(As2, 3, smem + 49152, goff, tid);
            mfma_chunk(smem,         Breg, bo2 + 0,  q, s, acc);
  WAITB(8); mfma_chunk(smem + 16384, Breg, bo2 + 4,  q, s, acc);
  WAITB(4); mfma_chunk(smem + 32768, Breg, bo2 + 8,  q, s, acc);
  WAITB(0); mfma_chunk(smem + 49152, Breg, bo2 + 12, q, s, acc);
}

// ---- fused LSTM epilogue. R10: single 8B store per lane at a PRECOMPUTED
// octet-layout offset (hoff) -> wave's 64 stores span a contiguous 1KB, the
// block's 4 waves fully cover every 64B line (no partial-sector writes). ----
__device__ __forceinline__ void epilogue(
    const f32x4* __restrict__ acc, float* __restrict__ tbuf, ushort* __restrict__ hsh,
    const f32x4 bz, const f32x4* w01, const f32x4* w23, const float2* xr,
    float* __restrict__ creg, __hip_bfloat16* __restrict__ hout,
    int hoff, int lane) {
  const int s = lane & 15, q = lane >> 4;
  const int row_e = lane >> 2, jl = lane & 3;
#pragma unroll
  for (int mi = 0; mi < 4; ++mi) {
#pragma unroll
    for (int r = 0; r < 4; ++r)
      tbuf[mi * 320 + (q * 4 + r) * 20 + s] = acc[mi][r];
  }
#pragma unroll
  for (int mi = 0; mi < 4; ++mi) {
    f32x4 gv = *(const f32x4*)&tbuf[mi * 320 + row_e * 20 + jl * 4];
    float gi = gv[0] + bz[0], gf = gv[1] + bz[1];
    float gg = gv[2] + bz[2], go = gv[3] + bz[3];
    if (xr) {
      gi += xr[mi].x * (*w01)[0] + xr[mi].y * (*w01)[1];
      gf += xr[mi].x * (*w01)[2] + xr[mi].y * (*w01)[3];
      gg += xr[mi].x * (*w23)[0] + xr[mi].y * (*w23)[1];
      go += xr[mi].x * (*w23)[2] + xr[mi].y * (*w23)[3];
    }
    float iv = sigm(gi), fv = sigm(gf), gvv = tanhf(gg), ov = sigm(go);
    float cv = fv * creg[mi] + iv * gvv;
    creg[mi] = cv;
    __hip_bfloat16 hv = __float2bfloat16(ov * tanhf(cv));
    hsh[(mi << 6) + lane] = __builtin_bit_cast(unsigned short, hv);
  }
  unsigned long long pk;
  asm volatile("" ::: "memory");
  __builtin_memcpy(&pk, &hsh[lane << 2], 8);        // aliasing-safe (R8 lesson)
  __hip_atomic_store((unsigned long long*)(hout + hoff),
                     pk, __ATOMIC_RELAXED, __HIP_MEMORY_SCOPE_AGENT);
}

// pred over all 32 sibling blocks: 2 batch rows each; octet-layout gather
__device__ __forceinline__ void pred_job2(const __hip_bfloat16* h2, const float* fcW,
                                          const float* fcb, float* outp,
                                          int d2, int g, int nt) {
  const int wv = threadIdx.x >> 6, lane = threadIdx.x & 63;
  if (wv < 2) {
    const int bl = nt * 2 + wv;              // row within group
    const int b = g * 64 + bl;
    float s0 = 0.f, s1 = 0.f;
    for (int k = lane; k < 512; k += 64) {
      const int unit = ((g * 4 + (k >> 7)) * 16 + ((k >> 3) & 15)) * 64 + bl;
      float hv = __bfloat162float(h2[(size_t)unit * 8 + (k & 7)]);
      s0 += hv * fcW[k];
      s1 += hv * fcW[512 + k];
    }
    for (int off = 32; off; off >>= 1) {
      s0 += __shfl_down(s0, off);
      s1 += __shfl_down(s1, off);
    }
    if (lane == 0) {
      outp[(size_t)b * (HOR * 2) + d2 * 2]     = s0 + fcb[0];
      outp[(size_t)b * (HOR * 2) + d2 * 2 + 1] = s1 + fcb[1];
    }
  }
}

// Persistent kernel: 512 blocks, 2/CU by construction (LDS 64 KB, VGPR capped).
__global__ __launch_bounds__(256, 2) void seq2seq_persistent(PK p) {
  __shared__ __align__(16) char smem[65536];   // 4x16KB staging; tbuf/hsh alias
  const int blk = blockIdx.x;
  const int g = blk & 7;
  const int role = (blk >> 3) & 1;
  const int nt = blk >> 4;                     // 0..31 gate-col tile
  const int goff = g * 4;
  const int wv = threadIdx.x >> 6, lane = threadIdx.x & 63;
  const int s16 = lane & 15, q = lane >> 4;
  const int nrow = nt * 64 + wv * 16 + s16;    // B-frag gate-col row
  const int jg = nt * 16 + wv * 4 + (lane & 3);
  const int n4 = jg * 4;
  // octet-layout store offset (step-invariant): c=nt>>3, o=(2nt+(wv>>1))&15, e0=(wv&1)*4
  const int hoff = (((goff + (nt >> 3)) * 16 + ((2 * nt + (wv >> 1)) & 15)) * 64 + lane) * 8
                   + (wv & 1) * 4;
  float* tbuf = (float*)(smem) + wv * 1280;            // per-wave 5 KB
  ushort* hsh = (ushort*)(smem + 20480) + wv * 256;    // per-wave 512 B

  f32x4 acc[4];
  bf16x8 Breg[32];                             // 128 regs of weights
  float creg[4] = {0.f, 0.f, 0.f, 0.f};        // cell state, register-resident

  if (role == 1) {
    // ---- role B: encoder layer1, decoder cell2 ----
    // Encoder (R8 ordering): h0[u] (cross, EARLY — role A runs ahead) waited at
    // top + staged first (W cols 0..511 = Breg 0..15); own critical chain flag
    // f1[u-1] polled mid-GEMM before the h1[u-1] half (Breg 16..31).
    load_w<32>(Breg, p.W1c, 1024, nrow, q);
    f32x4 bz = *(const f32x4*)&p.b1r[n4];
    for (int u = 0; u < TT; ++u) {
      waitflag_nb(FL(p.f0, u, g));
      const __hip_bfloat16* A2 = (u == 0) ? p.zbuf : p.h1buf + (size_t)(u - 1) * SLOT;
      int* f2 = (u == 0) ? nullptr : FL(p.f1, u - 1, g);
      gemm8(p.h0buf + (size_t)u * SLOT, 0, A2, 16, f2, Breg, goff, smem, lane, acc);
      epilogue(acc, tbuf, hsh, bz, nullptr, nullptr, nullptr, creg,
               p.h1buf + (size_t)u * SLOT, hoff, lane);
      arrive(FL(p.f1, u, g));
    }
    // Decoder (R9 ordering): own dh2[d-1] (EARLY) first (Breg 16..31 = dWhh1);
    // cross fd1[d] (LATE — immediately preceding link) polled mid-GEMM.
    load_w<32>(Breg, p.Wd1c, 1024, nrow, q);
    bz = *(const f32x4*)&p.bd1r[n4];
    for (int d = 0; d < HOR; ++d) {
      if (d == 0) waitflag_nb(FL(p.f1, 127, g));
      else        waitflag_nb(FL(p.fd2, d - 1, g));
      const __hip_bfloat16* Af = (d == 0) ? p.h1buf + (size_t)127 * SLOT
                                          : p.dh2buf + (size_t)(d - 1) * SLOT;
      gemm8(Af, 16, p.dh1buf + (size_t)d * SLOT, 0, FL(p.fd1, d, g),
            Breg, goff, smem, lane, acc);
      epilogue(acc, tbuf, hsh, bz, nullptr, nullptr, nullptr, creg,
               p.dh2buf + (size_t)d * SLOT, hoff, lane);
      arrive(FL(p.fd2, d, g));
    }
  } else {
    // ---- role A: encoder layer0 (K=512), decoder cell1 (pred folded) ----
    load_w<16>(Breg, p.W0r, 512, nrow, q);
    f32x4 bz = *(const f32x4*)&p.b0r[n4];
    f32x4 w01 = *(const f32x4*)&p.Wx0r[n4 * 2];
    f32x4 w23 = *(const f32x4*)&p.Wx0r[n4 * 2 + 4];
    const int row_e = lane >> 2;
    const int m0 = g * 64;
    for (int s = 0; s < TT; ++s) {
      if (s >= 1) waitflag_nb(FL(p.f0, s - 1, g));
      gemm4((s == 0) ? p.zbuf : p.h0buf + (size_t)(s - 1) * SLOT,
            Breg, goff, smem, lane, acc);
      float2 xr[4];
#pragma unroll
      for (int mi = 0; mi < 4; ++mi)
        xr[mi] = *(const float2*)&p.x[((size_t)(m0 + mi * 16 + row_e) * TT + s) * 2];
      epilogue(acc, tbuf, hsh, bz, &w01, &w23, xr, creg,
               p.h0buf + (size_t)s * SLOT, hoff, lane);
      arrive(FL(p.f0, s, g));
    }
    // Decoder (R9 ordering): own dh1[d-1] (EARLY) first (Breg 0..15 = dWhh0);
    // cross fd2[d-1] (LATE) polled mid-GEMM before the dh2[d-1] half.
    load_w<32>(Breg, p.Wd0c, 1024, nrow, q);
    f32x4 bzd0 = *(const f32x4*)&p.bd0s0[n4];
    f32x4 bzd  = *(const f32x4*)&p.bd0r[n4];
    for (int d = 0; d < HOR; ++d) {
      const __hip_bfloat16 *Af, *As2; int* f2; f32x4 bzu;
      if (d == 0) {
        waitflag_nb(FL(p.f0, 127, g));
        Af = p.h0buf + (size_t)127 * SLOT; As2 = p.zbuf; f2 = nullptr; bzu = bzd0;
      } else {
        waitflag_nb(FL(p.fd1, d - 1, g));
        Af  = p.dh1buf + (size_t)(d - 1) * SLOT;
        As2 = p.dh2buf + (size_t)(d - 1) * SLOT;
        f2 = FL(p.fd2, d - 1, g); bzu = bzd;
      }
      gemm8(Af, 0, As2, 16, f2, Breg, goff, smem, lane, acc);
      epilogue(acc, tbuf, hsh, bzu, nullptr, nullptr, nullptr, creg,
               p.dh1buf + (size_t)d * SLOT, hoff, lane);
      arrive(FL(p.fd1, d, g));
      if (d >= 1)
        pred_job2(p.dh2buf + (size_t)(d - 1) * SLOT, p.fcW, p.fcb, p.out, d - 1, g, nt);
    }
    waitflag_nb(FL(p.fd2, 23, g));
    pred_job2(p.dh2buf + (size_t)23 * SLOT, p.fcW, p.fcb, p.out, 23, g, nt);
  }
}

// Build gate-interleaved bf16 weights, combined biases, and the pred-fold:
// Wd0c[:,512:1024] = dWih0 @ fcW  (rank-2 fold of decoder feedback)
__global__ void prep_weights(
    const float* eWih0, const float* eWhh0, const float* ebih0, const float* ebhh0,
    const float* eWih1, const float* eWhh1, const float* ebih1, const float* ebhh1,
    const float* dWih0, const float* dWhh0, const float* dbih0, const float* dbhh0,
    const float* dWih1, const float* dWhh1, const float* dbih1, const float* dbhh1,
    const float* fcW, const float* fcb,
    __hip_bfloat16* W0r, __hip_bfloat16* W1c, __hip_bfloat16* Wd0c, __hip_bfloat16* Wd1c,
    float* b0r, float* b1r, float* bd0s0, float* bd0r, float* bd1r, float* Wx0r) {
  long idx = (long)blockIdx.x * blockDim.x + threadIdx.x;
  if (idx >= (long)G4 * 3584) return;
  int np = (int)(idx / 3584), kk = (int)(idx % 3584);
  int g = np & 3, j = np >> 2;
  int srow = g * HID + j;
  if (kk < 512) {
    W0r[(size_t)np * 512 + kk] = __float2bfloat16(eWhh0[(size_t)srow * 512 + kk]);
  } else if (kk < 1536) {
    int k2 = kk - 512;
    float v = (k2 < 512) ? eWih1[(size_t)srow * 512 + k2] : eWhh1[(size_t)srow * 512 + (k2 - 512)];
    W1c[(size_t)np * 1024 + k2] = __float2bfloat16(v);
  } else if (kk < 2560) {
    int k2 = kk - 1536;
    float v;
    if (k2 < 512) v = dWhh0[(size_t)srow * 512 + k2];
    else {
      int k3 = k2 - 512;
      v = dWih0[srow * 2] * fcW[k3] + dWih0[srow * 2 + 1] * fcW[512 + k3];
    }
    Wd0c[(size_t)np * 1024 + k2] = __float2bfloat16(v);
  } else {
    int k2 = kk - 2560;
    float v = (k2 < 512) ? dWih1[(size_t)srow * 512 + k2] : dWhh1[(size_t)srow * 512 + (k2 - 512)];
    Wd1c[(size_t)np * 1024 + k2] = __float2bfloat16(v);
  }
  if (kk == 0) {
    b0r[np] = ebih0[srow] + ebhh0[srow];
    b1r[np] = ebih1[srow] + ebhh1[srow];
    float bs0 = dbih0[srow] + dbhh0[srow];
    bd0s0[np] = bs0;
    bd0r[np] = bs0 + dWih0[srow * 2] * fcb[0] + dWih0[srow * 2 + 1] * fcb[1];
    bd1r[np] = dbih1[srow] + dbhh1[srow];
    Wx0r[np * 2]     = eWih0[srow * 2];
    Wx0r[np * 2 + 1] = eWih0[srow * 2 + 1];
  }
}

extern "C" void kernel_launch(void* const* d_in, const int* in_sizes, int n_in,
                              void* d_out, int out_size, void* d_ws, size_t ws_size,
                              hipStream_t stream) {
  (void)in_sizes; (void)n_in; (void)out_size; (void)ws_size;
  const float* x     = (const float*)d_in[0];
  const float* eWih0 = (const float*)d_in[1];
  const float* eWhh0 = (const float*)d_in[2];
  const float* ebih0 = (const float*)d_in[3];
  const float* ebhh0 = (const float*)d_in[4];
  const float* eWih1 = (const float*)d_in[5];
  const float* eWhh1 = (const float*)d_in[6];
  const float* ebih1 = (const float*)d_in[7];
  const float* ebhh1 = (const float*)d_in[8];
  const float* dWih0 = (const float*)d_in[9];
  const float* dWhh0 = (const float*)d_in[10];
  const float* dbih0 = (const float*)d_in[11];
  const float* dbhh0 = (const float*)d_in[12];
  const float* dWih1 = (const float*)d_in[13];
  const float* dWhh1 = (const float*)d_in[14];
  const float* dbih1 = (const float*)d_in[15];
  const float* dbhh1 = (const float*)d_in[16];
  const float* fcW   = (const float*)d_in[17];
  const float* fcb   = (const float*)d_in[18];

  char* ws = (char*)d_ws;
  size_t off = 0;
  auto alloc = [&](size_t bytes) -> char* {
    char* pp = ws + off;
    off = (off + bytes + 255) & ~(size_t)255;
    return pp;
  };

  __hip_bfloat16* W0r  = (__hip_bfloat16*)alloc((size_t)G4 * 512 * 2);
  __hip_bfloat16* W1c  = (__hip_bfloat16*)alloc((size_t)G4 * 1024 * 2);
  __hip_bfloat16* Wd0c = (__hip_bfloat16*)alloc((size_t)G4 * 1024 * 2);
  __hip_bfloat16* Wd1c = (__hip_bfloat16*)alloc((size_t)G4 * 1024 * 2);
  float* b0r   = (float*)alloc(G4 * 4);
  float* b1r   = (float*)alloc(G4 * 4);
  float* bd0s0 = (float*)alloc(G4 * 4);
  float* bd0r  = (float*)alloc(G4 * 4);
  float* bd1r  = (float*)alloc(G4 * 4);
  float* Wx0r  = (float*)alloc(G4 * 2 * 4);

  __hip_bfloat16* h0buf  = (__hip_bfloat16*)alloc((size_t)TT * SLOT * 2);
  __hip_bfloat16* h1buf  = (__hip_bfloat16*)alloc((size_t)TT * SLOT * 2);
  __hip_bfloat16* dh1buf = (__hip_bfloat16*)alloc((size_t)HOR * SLOT * 2);
  __hip_bfloat16* dh2buf = (__hip_bfloat16*)alloc((size_t)HOR * SLOT * 2);

  char* zbase = ws + off;
  __hip_bfloat16* zbuf = (__hip_bfloat16*)alloc((size_t)SLOT * 2);
  int* f0  = (int*)alloc(TT * 8 * 16 * 4);
  int* f1  = (int*)alloc(TT * 8 * 16 * 4);
  int* fd1 = (int*)alloc(HOR * 8 * 16 * 4);
  int* fd2 = (int*)alloc(HOR * 8 * 16 * 4);
  size_t zbytes = (size_t)((ws + off) - zbase);

  hipMemsetAsync(zbase, 0, zbytes, stream);
  prep_weights<<<(int)(((long)G4 * 3584 + 255) / 256), 256, 0, stream>>>(
      eWih0, eWhh0, ebih0, ebhh0, eWih1, eWhh1, ebih1, ebhh1,
      dWih0, dWhh0, dbih0, dbhh0, dWih1, dWhh1, dbih1, dbhh1,
      fcW, fcb, W0r, W1c, Wd0c, Wd1c, b0r, b1r, bd0s0, bd0r, bd1r, Wx0r);

  PK p;
  p.x = x;
  p.W0r = W0r; p.W1c = W1c; p.Wd0c = Wd0c; p.Wd1c = Wd1c;
  p.b0r = b0r; p.b1r = b1r; p.bd0s0 = bd0s0; p.bd0r = bd0r; p.bd1r = bd1r; p.Wx0r = Wx0r;
  p.fcW = fcW; p.fcb = fcb;
  p.h0buf = h0buf; p.h1buf = h1buf; p.dh1buf = dh1buf; p.dh2buf = dh2buf;
  p.zbuf = zbuf;
  p.f0 = f0; p.f1 = f1; p.fd1 = fd1; p.fd2 = fd2;
  p.out = (float*)d_out;

  seq2seq_persistent<<<512, 256, 0, stream>>>(p);
}